// Round 6
// baseline (156.523 us; speedup 1.0000x reference)
//
#include <hip/hip_runtime.h>
#include <cstddef>

// ---------------------------------------------------------------------------
// MHA block: y = attn(x@Wqkv+b) @ Wo + bo   (B=16,T=512,C=1024,H=16,hd=64)
// R6: QKV GEMM -> m201-style 4-phase schedule (A tribuf, B dbuf, vmcnt(7));
//     attention -> persistent-head blocks (grid 256x2, qt-loop in-kernel).
// ---------------------------------------------------------------------------

#define B_  16
#define T_  512
#define C_  1024
#define H_  16
#define HD_ 64

typedef __bf16 bf16x8 __attribute__((ext_vector_type(8)));
typedef float  f32x4  __attribute__((ext_vector_type(4)));

__device__ __forceinline__ void gload16(const void* g, void* lds_dst) {
  __builtin_amdgcn_global_load_lds(
      (const __attribute__((address_space(1))) unsigned int*)g,
      (__attribute__((address_space(3))) unsigned int*)lds_dst, 16, 0, 0);
}

// ------------------------- convert x: fp32 -> bf16 --------------------------
__global__ void cvt_kernel(const float* __restrict__ in, __bf16* __restrict__ out, int n) {
  int i = (blockIdx.x * 256 + threadIdx.x) * 8;
  if (i >= n) return;
  float4 f0 = *(const float4*)&in[i];
  float4 f1 = *(const float4*)&in[i + 4];
  bf16x8 o;
  o[0] = (__bf16)f0.x; o[1] = (__bf16)f0.y; o[2] = (__bf16)f0.z; o[3] = (__bf16)f0.w;
  o[4] = (__bf16)f1.x; o[5] = (__bf16)f1.y; o[6] = (__bf16)f1.z; o[7] = (__bf16)f1.w;
  *(bf16x8*)&out[i] = o;
}

// -------------- transpose+convert: w[K][N] fp32 -> wt[N][K] bf16 ------------
__global__ void tconv_kernel(const float* __restrict__ w, __bf16* __restrict__ wt,
                             int K, int N) {
  __shared__ float tile[32][33];
  int tx = threadIdx.x, ty = threadIdx.y;          // block (32,8)
  int n0 = blockIdx.x * 32, k0 = blockIdx.y * 32;
  #pragma unroll
  for (int i = 0; i < 4; ++i) {
    int r = ty + i * 8;
    tile[r][tx] = w[(size_t)(k0 + r) * N + n0 + tx];
  }
  __syncthreads();
  #pragma unroll
  for (int i = 0; i < 4; ++i) {
    int r = ty + i * 8;
    wt[(size_t)(n0 + r) * K + k0 + tx] = (__bf16)tile[tx][r];
  }
}

// ---------------- V transpose: v[bh][t][d] -> vt[bh][d][t] ------------------
__global__ void vtr_kernel(const __bf16* __restrict__ v, __bf16* __restrict__ vt) {
  __shared__ __bf16 tile[64][68];
  const int tid = threadIdx.x;
  const int bh = blockIdx.x, tc = blockIdx.y;      // 64-row t-chunk
  const size_t base = (size_t)bh * T_ * HD_;
  #pragma unroll
  for (int p = 0; p < 2; ++p) {
    int t8 = p * 256 + tid;
    int r = t8 >> 3, col = (t8 & 7) * 8;
    *(bf16x8*)&tile[r][col] =
        *(const bf16x8*)&v[base + (size_t)(tc * 64 + r) * HD_ + col];
  }
  __syncthreads();
  #pragma unroll
  for (int p = 0; p < 2; ++p) {
    int t8 = p * 256 + tid;
    int d = t8 >> 3, tt = (t8 & 7) * 8;
    bf16x8 o;
    #pragma unroll
    for (int i = 0; i < 8; ++i) o[i] = tile[tt + i][d];
    *(bf16x8*)&vt[base + (size_t)d * T_ + tc * 64 + tt] = o;
  }
}

// ---------------------------------------------------------------------------
// QKV GEMM, 4-phase m201-style.
// Tile 256x192, BK=64, 8 waves (2M x 4N), per-wave 128x48 (8x3 16x16 frags).
// LDS 144KB: A TRIbuf 3x32KB @0, B dbuf 2x24KB @96KB. XOR swizzle on frag
// reads; staging pre-swizzles the GLOBAL source so gload_lds dest is linear.
// Per K-tile t (Abuf t%3, Bbuf t&1), 4 phases, each:
//   {ds_reads ; stage issues ; s_barrier ; lgkmcnt(0) ; sched_barrier ;
//    setprio(1) 12 MFMA setprio(0) ; s_barrier}
//   ph0: rdB(6)+rdA g0(4) ; stage A(t+2) half0 (2)
//   ph1: rdA g1(4)        ; stage A(t+2) half1 (2)
//   ph2: rdA g2(4)        ; stage B(t+2) (3)
//   ph3: rdA g3(4)        ; tile-end: vmcnt(7) (or 0 if no stages this tile)
// Hazards: A(t+2)->buf (t+2)%3=(t-1)%3: t-1's reads retired (each phase's
// lgkm(0)) >= 2 barriers before. B(t+2)->buf t&1: B(t) reads retired at
// ph0's lgkm(0), >=2 barriers before ph2's stage. Entering ph0(t):
// outstanding = A(t+1)[4]+B(t+1)[3] staged in t-1 -> vmcnt(7) guarantees
// A(t),B(t) landed. Last-stage tile (t+2==nt): end with vmcnt(0).
// ---------------------------------------------------------------------------
__global__ __launch_bounds__(512, 2) void gemm192_kernel(
    const __bf16* __restrict__ A, const __bf16* __restrict__ BT,
    const float* __restrict__ bias, int K, int NBn,
    __bf16* __restrict__ oq, __bf16* __restrict__ okk, __bf16* __restrict__ ov)
{
  extern __shared__ __align__(16) char lds[];
  const int tid = threadIdx.x, lane = tid & 63, wid = tid >> 6;
  const int wm = wid >> 2, wn = wid & 3;          // 2M x 4N
  const int lr = lane & 15, lg = lane >> 4;

  // bijective XCD swizzle (gridDim.x % 8 == 0)
  const int cpx = gridDim.x >> 3;
  const int id = (blockIdx.x & 7) * cpx + (blockIdx.x >> 3);
  const int m0 = (id / NBn) * 256, n0 = (id % NBn) * 192;

  // staging: one issue = 512 lanes x 16B = 8KB = 64 rows of 128B
  const int r8  = wid * 8 + (lane >> 3);
  const int csw = ((lane & 7) ^ (lane >> 3)) * 8;     // pre-swizzled col (elems)

  auto stageA2 = [&](const __bf16* g, char* dst, int half) { // 2 of 4 issues
    #pragma unroll
    for (int i = 0; i < 2; ++i) {
      int ii = half * 2 + i;
      gload16(g + (size_t)(ii * 64 + r8) * K + csw, dst + ii * 8192 + wid * 1024);
    }
  };
  auto stageA4 = [&](const __bf16* g, char* dst) {           // full 256x64
    #pragma unroll
    for (int i = 0; i < 4; ++i)
      gload16(g + (size_t)(i * 64 + r8) * K + csw, dst + i * 8192 + wid * 1024);
  };
  auto stageB = [&](const __bf16* g, char* dst) {            // 192x64, 3 issues
    #pragma unroll
    for (int i = 0; i < 3; ++i)
      gload16(g + (size_t)(i * 64 + r8) * K + csw, dst + i * 8192 + wid * 1024);
  };

  auto rdAg = [&](bf16x8* d, const char* Ab, int g) {  // 4 x ds_read_b128
    #pragma unroll
    for (int mf2 = 0; mf2 < 2; ++mf2) {
      const char* rp = Ab + (wm * 128 + (g * 2 + mf2) * 16 + lr) * 128;
      #pragma unroll
      for (int ks = 0; ks < 2; ++ks)
        d[mf2 * 2 + ks] = *(const bf16x8*)(rp + (((ks << 2) + lg) ^ (lr & 7)) * 16);
    }
  };
  auto rdB = [&](bf16x8* d, const char* Bb) {          // 6 x ds_read_b128
    #pragma unroll
    for (int nf = 0; nf < 3; ++nf) {
      const char* rp = Bb + (wn * 48 + nf * 16 + lr) * 128;
      #pragma unroll
      for (int ks = 0; ks < 2; ++ks)
        d[nf * 2 + ks] = *(const bf16x8*)(rp + (((ks << 2) + lg) ^ (lr & 7)) * 16);
    }
  };

  f32x4 acc[8][3] = {};

  auto mmg = [&](int g, const bf16x8* av, const bf16x8* bv) {  // 12 MFMA
    __builtin_amdgcn_s_setprio(1);
    #pragma unroll
    for (int mf2 = 0; mf2 < 2; ++mf2)
      #pragma unroll
      for (int nf = 0; nf < 3; ++nf)
        #pragma unroll
        for (int ks = 0; ks < 2; ++ks)
          acc[g * 2 + mf2][nf] = __builtin_amdgcn_mfma_f32_16x16x32_bf16(
              av[mf2 * 2 + ks], bv[nf * 2 + ks], acc[g * 2 + mf2][nf], 0, 0, 0);
    __builtin_amdgcn_s_setprio(0);
  };

#define MIDBAR() do { \
    asm volatile("s_barrier\ns_waitcnt lgkmcnt(0)" ::: "memory"); \
    __builtin_amdgcn_sched_barrier(0); } while (0)
#define ENDBAR() asm volatile("s_barrier" ::: "memory")

  const int nt = K >> 6;                              // 16
  const __bf16* gA = A  + (size_t)m0 * K;
  const __bf16* gB = BT + (size_t)n0 * K;
  char* const Ab0 = lds;                              // 3 x 32KB
  char* const Bb0 = lds + 98304;                      // 2 x 24KB

  // prologue: A(0),B(0),A(1),B(1) -> 14 issues; drain oldest 7 = A0+B0
  stageA4(gA, Ab0);
  stageB(gB, Bb0);
  stageA4(gA + 64, Ab0 + 32768);
  stageB(gB + 64, Bb0 + 24576);
  asm volatile("s_waitcnt vmcnt(7)\ns_barrier" ::: "memory");

  bf16x8 a[4][4], b[6];

  for (int t = 0; t < nt; ++t) {
    const char* Ab = Ab0 + (t % 3) * 32768;
    const char* Bb = Bb0 + (t & 1) * 24576;
    char* Aw = Ab0 + ((t + 2) % 3) * 32768;
    char* Bw = Bb0 + (t & 1) * 24576;                 // (t+2)&1 == t&1
    const bool st = (t + 2 < nt);

    // ---- ph0 ----
    rdB(b, Bb);
    rdAg(a[0], Ab, 0);
    if (st) stageA2(gA + (size_t)(t + 2) * 64, Aw, 0);
    MIDBAR();
    mmg(0, a[0], b);
    ENDBAR();

    // ---- ph1 ----
    rdAg(a[1], Ab, 1);
    if (st) stageA2(gA + (size_t)(t + 2) * 64, Aw, 1);
    MIDBAR();
    mmg(1, a[1], b);
    ENDBAR();

    // ---- ph2 ----
    rdAg(a[2], Ab, 2);
    if (st) stageB(gB + (size_t)(t + 2) * 64, Bw);
    MIDBAR();
    mmg(2, a[2], b);
    ENDBAR();

    // ---- ph3 ----
    rdAg(a[3], Ab, 3);
    MIDBAR();
    mmg(3, a[3], b);
    if (st) { asm volatile("s_waitcnt vmcnt(7)\ns_barrier" ::: "memory"); }
    else    { asm volatile("s_waitcnt vmcnt(0)\ns_barrier" ::: "memory"); }
  }
#undef MIDBAR
#undef ENDBAR

  // ---- epilogue: split q/k/v; D row = lg*4+j, col = lr per 16x16 frag ----
  #pragma unroll
  for (int nf = 0; nf < 3; ++nf) {
    int n = n0 + wn * 48 + nf * 16 + lr;
    float bv = bias[n];
    int which = n >> 10;
    __bf16* dst = (which == 0) ? oq : (which == 1) ? okk : ov;
    int h = (n >> 6) & 15, d = n & 63;
    #pragma unroll
    for (int mf = 0; mf < 8; ++mf)
      #pragma unroll
      for (int j = 0; j < 4; ++j) {
        int m = m0 + wm * 128 + mf * 16 + lg * 4 + j;
        int bb = m >> 9, tt = m & 511;
        dst[(size_t)((bb * H_ + h) * T_ + tt) * HD_ + d] =
            (__bf16)(acc[mf][nf][j] + bv);
      }
  }
}

// ---------------------------------------------------------------------------
// Out-proj GEMM (R4-proven): C[M][N] = A@BT^T + bias, fp32 out.
// Tile 128x256, BK=64, 8 waves (2M x 4N), per-wave 64x64.
// ---------------------------------------------------------------------------
__global__ __launch_bounds__(512, 2) void gemm128_kernel(
    const __bf16* __restrict__ A, const __bf16* __restrict__ BT,
    const float* __restrict__ bias, int K, int NBn, int N,
    float* __restrict__ out32)
{
  extern __shared__ __align__(16) char lds[];
  const int tid = threadIdx.x, lane = tid & 63, wid = tid >> 6;
  const int wm = wid >> 2, wn = wid & 3;
  const int lr = lane & 15, lg = lane >> 4;

  const int cpx = gridDim.x >> 3;
  const int id = (blockIdx.x & 7) * cpx + (blockIdx.x >> 3);
  const int m0 = (id / NBn) * 128, n0 = (id % NBn) * 256;

  const int r8  = wid * 8 + (lane >> 3);
  const int csw = ((lane & 7) ^ (lane >> 3)) * 8;

  auto stageA = [&](const __bf16* g, char* dst) {
    #pragma unroll
    for (int i = 0; i < 2; ++i)
      gload16(g + (size_t)(i * 64 + r8) * K + csw, dst + i * 8192 + wid * 1024);
  };
  auto stageB = [&](const __bf16* g, char* dst) {
    #pragma unroll
    for (int i = 0; i < 4; ++i)
      gload16(g + (size_t)(i * 64 + r8) * K + csw, dst + i * 8192 + wid * 1024);
  };

  auto rdA = [&](bf16x8* d, const char* Ab) {
    #pragma unroll
    for (int mf = 0; mf < 4; ++mf) {
      const char* rp = Ab + (wm * 64 + mf * 16 + lr) * 128;
      #pragma unroll
      for (int ks = 0; ks < 2; ++ks)
        d[mf * 2 + ks] = *(const bf16x8*)(rp + (((ks << 2) + lg) ^ (lr & 7)) * 16);
    }
  };
  auto rdB = [&](bf16x8* d, const char* Bb, int nh) {
    #pragma unroll
    for (int nfl = 0; nfl < 2; ++nfl) {
      const char* rp = Bb + (wn * 64 + (nh * 2 + nfl) * 16 + lr) * 128;
      #pragma unroll
      for (int ks = 0; ks < 2; ++ks)
        d[nfl * 2 + ks] = *(const bf16x8*)(rp + (((ks << 2) + lg) ^ (lr & 7)) * 16);
    }
  };

  f32x4 acc[4][4] = {};

  auto mm = [&](const bf16x8* av, const bf16x8* bv, int nh) {
    __builtin_amdgcn_s_setprio(1);
    #pragma unroll
    for (int mf = 0; mf < 4; ++mf)
      #pragma unroll
      for (int nfl = 0; nfl < 2; ++nfl)
        #pragma unroll
        for (int ks = 0; ks < 2; ++ks)
          acc[mf][nh * 2 + nfl] = __builtin_amdgcn_mfma_f32_16x16x32_bf16(
              av[mf * 2 + ks], bv[nfl * 2 + ks], acc[mf][nh * 2 + nfl], 0, 0, 0);
    __builtin_amdgcn_s_setprio(0);
  };

  const int nt = K >> 6;
  const __bf16* gA = A  + (size_t)m0 * K;
  const __bf16* gB = BT + (size_t)n0 * K;
  char* const Ab0 = lds;
  char* const Bb0 = lds + 32768;

  stageB(gB, Bb0);
  stageA(gA, Ab0);
  stageB(gB + 64, Bb0 + 32768);
  stageA(gA + 64, Ab0 + 16384);

  bf16x8 a[8], b0[4], b1[4];

  for (int t = 0; t < nt; ++t) {
    char* Ab = Ab0 + (t & 1) * 16384;
    char* Bb = Bb0 + (t % 3) * 32768;

    if (t + 1 < nt) { asm volatile("s_waitcnt vmcnt(6)\ns_barrier" ::: "memory"); }
    else            { asm volatile("s_waitcnt vmcnt(0)\ns_barrier" ::: "memory"); }
    rdA(a, Ab);
    rdB(b0, Bb, 0);
    if (t + 2 < nt) stageB(gB + (size_t)(t + 2) * 64, Bb0 + ((t + 2) % 3) * 32768);
    mm(a, b0, 0);
    asm volatile("s_barrier" ::: "memory");

    rdB(b1, Bb, 1);
    if (t + 2 < nt) stageA(gA + (size_t)(t + 2) * 64, Ab);
    mm(a, b1, 1);
    asm volatile("s_barrier" ::: "memory");
  }

  #pragma unroll
  for (int nf = 0; nf < 4; ++nf) {
    int n = n0 + wn * 64 + nf * 16 + lr;
    float bv = bias[n];
    #pragma unroll
    for (int mf = 0; mf < 4; ++mf)
      #pragma unroll
      for (int j = 0; j < 4; ++j) {
        int m = m0 + wm * 64 + mf * 16 + lg * 4 + j;
        out32[(size_t)m * N + n] = acc[mf][nf][j] + bv;
      }
  }
}

// ---------------------------------------------------------------------------
// Persistent-head flash attention (causal). Grid (256 heads, 2 parities).
// Block (bh,par) processes qt = par, par+2, par+4, par+6 sequentially —
// K/V chunks of its head re-read through the same XCD's L2 (id and id+256
// land on the same XCD). 4 waves, each wave 16 q-rows of the current qt.
// V pre-transposed (vt[bh][d][t]); K/V double-staged via registers.
// ---------------------------------------------------------------------------
__global__ __launch_bounds__(256, 2) void attn_kernel(
    const __bf16* __restrict__ qb, const __bf16* __restrict__ kb,
    const __bf16* __restrict__ vtb, __bf16* __restrict__ y)
{
  __shared__ __attribute__((aligned(16))) __bf16 Ks[64][72];
  __shared__ __attribute__((aligned(16))) __bf16 Vt[64][72];
  __shared__ __attribute__((aligned(16))) __bf16 Ps[4][16][72];

  const int tid = threadIdx.x, lane = tid & 63, w = tid >> 6;
  const int lr = lane & 15, lg = lane >> 4;
  const int bh = blockIdx.x, par = blockIdx.y;
  const size_t base = (size_t)bh * T_ * HD_;
  const float SCALE = 0.03125f;                   // 1/sqrt(1024)
  const float L2E = 1.44269504088896f;

  const int r_  = tid >> 3;                       // 0..31 (+32 for p=1)
  const int c8_ = (tid & 7) * 8;
  const int b = bh >> 4, h = bh & 15;

  // prefetch chunk 0 (first chunk of first qt for both parities)
  bf16x8 kk[2], vv[2], kk2[2], vv2[2];
  #pragma unroll
  for (int p = 0; p < 2; ++p) {
    int rr = p * 32 + r_;
    kk[p] = *(const bf16x8*)&kb[base + (size_t)rr * HD_ + c8_];
    vv[p] = *(const bf16x8*)&vtb[base + (size_t)rr * T_ + c8_];
  }

  for (int qt = par; qt < 8; qt += 2) {
    const int q0 = qt * 64 + w * 16;

    bf16x8 qf[2];
    #pragma unroll
    for (int s = 0; s < 2; ++s)
      qf[s] = *(const bf16x8*)&qb[base + (size_t)(q0 + lr) * HD_ + s * 32 + lg * 8];

    f32x4 acc[4] = {};
    float mrun[4] = { -__builtin_inff(), -__builtin_inff(),
                      -__builtin_inff(), -__builtin_inff() };
    float lrun[4] = { 0.f, 0.f, 0.f, 0.f };

    for (int c = 0; c <= qt; ++c) {
      // ---- write staged regs to LDS ----
      #pragma unroll
      for (int p = 0; p < 2; ++p) {
        int rr = p * 32 + r_;
        *(bf16x8*)&Ks[rr][c8_] = kk[p];
        *(bf16x8*)&Vt[rr][c8_] = vv[p];
      }
      __syncthreads();

      // ---- prefetch next chunk (chunk 0 of next qt when c==qt) ----
      {
        int nc = (c < qt) ? c + 1 : 0;
        #pragma unroll
        for (int p = 0; p < 2; ++p) {
          int rr = p * 32 + r_;
          kk2[p] = *(const bf16x8*)&kb[base + (size_t)nc * 64 * HD_ + (size_t)rr * HD_ + c8_];
          vv2[p] = *(const bf16x8*)&vtb[base + (size_t)rr * T_ + nc * 64 + c8_];
        }
      }

      // ---- S = Q K^T (16 q x 64 kv) ----
      f32x4 sc[4] = {};
      #pragma unroll
      for (int s = 0; s < 2; ++s) {
        #pragma unroll
        for (int cc = 0; cc < 4; ++cc) {
          bf16x8 kf = *(const bf16x8*)&Ks[cc * 16 + lr][s * 32 + lg * 8];
          sc[cc] = __builtin_amdgcn_mfma_f32_16x16x32_bf16(qf[s], kf, sc[cc], 0, 0, 0);
        }
      }

      // ---- scale + causal mask ----
      #pragma unroll
      for (int cc = 0; cc < 4; ++cc)
        #pragma unroll
        for (int j = 0; j < 4; ++j) {
          float v = sc[cc][j] * SCALE;
          if (c == qt) {
            int kv = c * 64 + cc * 16 + lr;
            int qr = q0 + lg * 4 + j;
            if (kv > qr) v = -__builtin_inff();
          }
          sc[cc][j] = v;
        }

      // ---- online softmax ----
      float mx[4];
      #pragma unroll
      for (int j = 0; j < 4; ++j)
        mx[j] = fmaxf(fmaxf(sc[0][j], sc[1][j]), fmaxf(sc[2][j], sc[3][j]));
      #pragma unroll
      for (int msk = 1; msk <= 8; msk <<= 1)
        #pragma unroll
        for (int j = 0; j < 4; ++j)
          mx[j] = fmaxf(mx[j], __shfl_xor(mx[j], msk, 64));
      float corr[4];
      #pragma unroll
      for (int j = 0; j < 4; ++j) {
        float nm = fmaxf(mrun[j], mx[j]);
        corr[j] = exp2f((mrun[j] - nm) * L2E);
        mrun[j] = nm;
      }
      #pragma unroll
      for (int cc = 0; cc < 4; ++cc)
        #pragma unroll
        for (int j = 0; j < 4; ++j)
          sc[cc][j] = exp2f((sc[cc][j] - mrun[j]) * L2E);
      float rs[4];
      #pragma unroll
      for (int j = 0; j < 4; ++j)
        rs[j] = sc[0][j] + sc[1][j] + sc[2][j] + sc[3][j];
      #pragma unroll
      for (int msk = 1; msk <= 8; msk <<= 1)
        #pragma unroll
        for (int j = 0; j < 4; ++j)
          rs[j] += __shfl_xor(rs[j], msk, 64);
      #pragma unroll
      for (int j = 0; j < 4; ++j)
        lrun[j] = lrun[j] * corr[j] + rs[j];
      #pragma unroll
      for (int dd = 0; dd < 4; ++dd)
        #pragma unroll
        for (int j = 0; j < 4; ++j)
          acc[dd][j] *= corr[j];

      // ---- P: C-layout -> A-layout via per-wave LDS ----
      #pragma unroll
      for (int cc = 0; cc < 4; ++cc)
        #pragma unroll
        for (int j = 0; j < 4; ++j)
          Ps[w][lg * 4 + j][cc * 16 + lr] = (__bf16)sc[cc][j];

      // ---- O += P V ----
      #pragma unroll
      for (int s = 0; s < 2; ++s) {
        bf16x8 pa = *(const bf16x8*)&Ps[w][lr][s * 32 + lg * 8];
        #pragma unroll
        for (int dd = 0; dd < 4; ++dd) {
          bf16x8 vf = *(const bf16x8*)&Vt[dd * 16 + lr][s * 32 + lg * 8];
          acc[dd] = __builtin_amdgcn_mfma_f32_16x16x32_bf16(pa, vf, acc[dd], 0, 0, 0);
        }
      }
      __syncthreads();
      #pragma unroll
      for (int p = 0; p < 2; ++p) { kk[p] = kk2[p]; vv[p] = vv2[p]; }
    }

    // ---- normalize + write y[B,T,C] for this qt ----
    #pragma unroll
    for (int dd = 0; dd < 4; ++dd)
      #pragma unroll
      for (int j = 0; j < 4; ++j) {
        int t = q0 + lg * 4 + j;
        int d = dd * 16 + lr;
        y[((size_t)(b * T_ + t)) * C_ + h * HD_ + d] = (__bf16)(acc[dd][j] / lrun[j]);
      }
  }
}

// ---------------------------------------------------------------------------
extern "C" void kernel_launch(void* const* d_in, const int* in_sizes, int n_in,
                              void* d_out, int out_size, void* d_ws, size_t ws_size,
                              hipStream_t stream) {
  const float* x    = (const float*)d_in[0];
  const float* wqkv = (const float*)d_in[1];
  const float* bqkv = (const float*)d_in[2];
  const float* wo   = (const float*)d_in[3];
  const float* bo   = (const float*)d_in[4];
  float* out = (float*)d_out;

  char* ws = (char*)d_ws;
  const size_t MB = 1u << 20;
  __bf16* xb    = (__bf16*)(ws);              // 16 MB  x bf16 [8192][1024]
  __bf16* wqt   = (__bf16*)(ws + 16 * MB);    //  6 MB  w_qkv^T bf16 [3072][1024]
  __bf16* wot   = (__bf16*)(ws + 22 * MB);    //  2 MB  w_o^T bf16 [1024][1024]
  __bf16* qbuf  = (__bf16*)(ws + 24 * MB);    // 16 MB  Q [B,H,T,HD]
  __bf16* kbuf  = (__bf16*)(ws + 40 * MB);    // 16 MB  K [B,H,T,HD]
  __bf16* vbuf  = (__bf16*)(ws + 56 * MB);    // 16 MB  V [B,H,T,HD]
  __bf16* ybuf  = (__bf16*)(ws + 56 * MB);    // aliases vbuf (dead after vtr)
  __bf16* vtbuf = (__bf16*)(ws + 72 * MB);    // 16 MB  V^T [B,H,HD,T]

  (void)hipFuncSetAttribute(reinterpret_cast<const void*>(&gemm192_kernel),
                            hipFuncAttributeMaxDynamicSharedMemorySize, 147456);
  (void)hipFuncSetAttribute(reinterpret_cast<const void*>(&gemm128_kernel),
                            hipFuncAttributeMaxDynamicSharedMemorySize, 131072);

  const int NX = B_ * T_ * C_;               // 8388608
  cvt_kernel<<<NX / (256 * 8), 256, 0, stream>>>(x, xb, NX);
  tconv_kernel<<<dim3(3 * C_ / 32, C_ / 32), dim3(32, 8), 0, stream>>>(wqkv, wqt, C_, 3 * C_);
  tconv_kernel<<<dim3(C_ / 32, C_ / 32), dim3(32, 8), 0, stream>>>(wo, wot, C_, C_);

  // QKV: 8192/256=32 x 3072/192=16 -> 512 blocks (2.0 rounds, 1 blk/CU)
  gemm192_kernel<<<512, 512, 147456, stream>>>(
      xb, wqt, bqkv, C_, 16, qbuf, kbuf, vbuf);

  vtr_kernel<<<dim3(B_ * H_, T_ / 64), 256, 0, stream>>>(vbuf, vtbuf);

  // persistent-head attention: 256 heads x 2 parities
  attn_kernel<<<dim3(B_ * H_, 2), 256, 0, stream>>>(qbuf, kbuf, vtbuf, ybuf);

  // out-proj: 64 x 4 -> 256 blocks (1.0 round)
  gemm128_kernel<<<256, 512, 131072, stream>>>(
      ybuf, wot, bo, C_, 4, C_, out);
}

// Round 7
// 155.645 us; speedup vs baseline: 1.0056x; 1.0056x over previous
//
#include <hip/hip_runtime.h>
#include <cstddef>

// ---------------------------------------------------------------------------
// MHA block: y = attn(x@Wqkv+b) @ Wo + bo   (B=16,T=512,C=1024,H=16,hd=64)
// R7: QKV -> m97-structure 128x128 GEMM (4 waves, 32KB LDS, 3 blocks/CU,
//     cross-block overlap). Attention -> one-block-per-head persistent
//     (K/V read exactly once; chunk-outer / qt-inner online softmax).
// ---------------------------------------------------------------------------

#define B_  16
#define T_  512
#define C_  1024
#define H_  16
#define HD_ 64

typedef __bf16 bf16x8 __attribute__((ext_vector_type(8)));
typedef float  f32x4  __attribute__((ext_vector_type(4)));

__device__ __forceinline__ void gload16(const void* g, void* lds_dst) {
  __builtin_amdgcn_global_load_lds(
      (const __attribute__((address_space(1))) unsigned int*)g,
      (__attribute__((address_space(3))) unsigned int*)lds_dst, 16, 0, 0);
}

// ------------------------- convert x: fp32 -> bf16 --------------------------
__global__ void cvt_kernel(const float* __restrict__ in, __bf16* __restrict__ out, int n) {
  int i = (blockIdx.x * 256 + threadIdx.x) * 8;
  if (i >= n) return;
  float4 f0 = *(const float4*)&in[i];
  float4 f1 = *(const float4*)&in[i + 4];
  bf16x8 o;
  o[0] = (__bf16)f0.x; o[1] = (__bf16)f0.y; o[2] = (__bf16)f0.z; o[3] = (__bf16)f0.w;
  o[4] = (__bf16)f1.x; o[5] = (__bf16)f1.y; o[6] = (__bf16)f1.z; o[7] = (__bf16)f1.w;
  *(bf16x8*)&out[i] = o;
}

// -------------- transpose+convert: w[K][N] fp32 -> wt[N][K] bf16 ------------
__global__ void tconv_kernel(const float* __restrict__ w, __bf16* __restrict__ wt,
                             int K, int N) {
  __shared__ float tile[32][33];
  int tx = threadIdx.x, ty = threadIdx.y;          // block (32,8)
  int n0 = blockIdx.x * 32, k0 = blockIdx.y * 32;
  #pragma unroll
  for (int i = 0; i < 4; ++i) {
    int r = ty + i * 8;
    tile[r][tx] = w[(size_t)(k0 + r) * N + n0 + tx];
  }
  __syncthreads();
  #pragma unroll
  for (int i = 0; i < 4; ++i) {
    int r = ty + i * 8;
    wt[(size_t)(n0 + r) * K + k0 + tx] = (__bf16)tile[tx][r];
  }
}

// ---------------- V transpose: v[bh][t][d] -> vt[bh][d][t] ------------------
__global__ void vtr_kernel(const __bf16* __restrict__ v, __bf16* __restrict__ vt) {
  __shared__ __bf16 tile[64][68];
  const int tid = threadIdx.x;
  const int bh = blockIdx.x, tc = blockIdx.y;      // 64-row t-chunk
  const size_t base = (size_t)bh * T_ * HD_;
  #pragma unroll
  for (int p = 0; p < 2; ++p) {
    int t8 = p * 256 + tid;
    int r = t8 >> 3, col = (t8 & 7) * 8;
    *(bf16x8*)&tile[r][col] =
        *(const bf16x8*)&v[base + (size_t)(tc * 64 + r) * HD_ + col];
  }
  __syncthreads();
  #pragma unroll
  for (int p = 0; p < 2; ++p) {
    int t8 = p * 256 + tid;
    int d = t8 >> 3, tt = (t8 & 7) * 8;
    bf16x8 o;
    #pragma unroll
    for (int i = 0; i < 8; ++i) o[i] = tile[tt + i][d];
    *(bf16x8*)&vt[base + (size_t)d * T_ + tc * 64 + tt] = o;
  }
}

// ---------------------------------------------------------------------------
// QKV GEMM, m97-structure: tile 128x128, BK=64, 256 threads (4 waves 2x2),
// wave 64x64 (4x4 16x16 frags), 32KB single-buffered static LDS ->
// ~3 blocks/CU: cross-block overlap hides the per-tile drain.
// Per K-tile: {rd a+b (16 b128); lgkm0+bar; stage(t+1) into SAME bufs
// (reads retired); 32 MFMA (covers stage latency); vmcnt0+bar}.
// XOR swizzle on frag reads; staging pre-swizzles the GLOBAL source.
// Epilogue splits q/k/v into [B,H,T,HD] bf16 with fused bias.
// ---------------------------------------------------------------------------
__global__ __launch_bounds__(256) void gemmsq_kernel(
    const __bf16* __restrict__ A, const __bf16* __restrict__ BT,
    const float* __restrict__ bias, int K, int NBn,
    __bf16* __restrict__ oq, __bf16* __restrict__ okk, __bf16* __restrict__ ov)
{
  __shared__ __attribute__((aligned(16))) char lds[32768];   // A 16KB | B 16KB
  const int tid = threadIdx.x, lane = tid & 63, wid = tid >> 6;  // 4 waves
  const int wm = wid >> 1, wn = wid & 1;          // 2M x 2N
  const int lr = lane & 15, lg = lane >> 4;

  const int cpx = gridDim.x >> 3;                 // bijective XCD swizzle
  const int id = (blockIdx.x & 7) * cpx + (blockIdx.x >> 3);
  const int m0 = (id / NBn) * 128, n0 = (id % NBn) * 128;

  // staging: one issue = 256 lanes x 16B = 4KB = 32 rows of 128B
  const int r8  = wid * 8 + (lane >> 3);          // 0..31
  const int csw = ((lane & 7) ^ (lane >> 3)) * 8; // pre-swizzled col (elems)

  auto stage = [&](const __bf16* g, char* dst) {  // 128x64 tile, 4 issues
    #pragma unroll
    for (int i = 0; i < 4; ++i)
      gload16(g + (size_t)(i * 32 + r8) * K + csw, dst + i * 4096 + wid * 1024);
  };
  auto rd = [&](bf16x8* d, const char* buf, int woff) {   // 8 x ds_read_b128
    #pragma unroll
    for (int f = 0; f < 4; ++f) {
      const char* rp = buf + (woff + f * 16 + lr) * 128;
      #pragma unroll
      for (int ks = 0; ks < 2; ++ks)
        d[f * 2 + ks] = *(const bf16x8*)(rp + (((ks << 2) + lg) ^ (lr & 7)) * 16);
    }
  };

  f32x4 acc[4][4] = {};
  const int nt = K >> 6;                          // 16
  const __bf16* gA = A  + (size_t)m0 * K;
  const __bf16* gB = BT + (size_t)n0 * K;
  char* const Ab = lds;
  char* const Bb = lds + 16384;

  stage(gA, Ab);
  stage(gB, Bb);
  asm volatile("s_waitcnt vmcnt(0)\ns_barrier" ::: "memory");

  bf16x8 a[8], b[8];
  for (int t = 0; t < nt; ++t) {
    rd(a, Ab, wm * 64);
    rd(b, Bb, wn * 64);
    asm volatile("s_waitcnt lgkmcnt(0)\ns_barrier" ::: "memory");  // reads in regs
    if (t + 1 < nt) {                                // overwrite is now safe
      stage(gA + (size_t)(t + 1) * 64, Ab);
      stage(gB + (size_t)(t + 1) * 64, Bb);
    }
    __builtin_amdgcn_s_setprio(1);
    #pragma unroll
    for (int mf = 0; mf < 4; ++mf)
      #pragma unroll
      for (int nf = 0; nf < 4; ++nf)
        #pragma unroll
        for (int ks = 0; ks < 2; ++ks)
          acc[mf][nf] = __builtin_amdgcn_mfma_f32_16x16x32_bf16(
              a[mf * 2 + ks], b[nf * 2 + ks], acc[mf][nf], 0, 0, 0);
    __builtin_amdgcn_s_setprio(0);
    asm volatile("s_waitcnt vmcnt(0)\ns_barrier" ::: "memory");    // t+1 landed
  }

  // ---- epilogue: split q/k/v; D row = lg*4+j, col = lr per 16x16 frag ----
  #pragma unroll
  for (int nf = 0; nf < 4; ++nf) {
    int n = n0 + wn * 64 + nf * 16 + lr;
    float bv = bias[n];
    int which = n >> 10;
    __bf16* dst = (which == 0) ? oq : (which == 1) ? okk : ov;
    int h = (n >> 6) & 15, d = n & 63;
    #pragma unroll
    for (int mf = 0; mf < 4; ++mf)
      #pragma unroll
      for (int j = 0; j < 4; ++j) {
        int m = m0 + wm * 64 + mf * 16 + lg * 4 + j;
        int bb = m >> 9, tt = m & 511;
        dst[(size_t)((bb * H_ + h) * T_ + tt) * HD_ + d] =
            (__bf16)(acc[mf][nf][j] + bv);
      }
  }
}

// ---------------------------------------------------------------------------
// Out-proj GEMM (R4/R5-proven): C[M][N] = A@BT^T + bias, fp32 out.
// Tile 128x256, BK=64, 8 waves (2M x 4N), per-wave 64x64.
// ---------------------------------------------------------------------------
__global__ __launch_bounds__(512, 2) void gemm128_kernel(
    const __bf16* __restrict__ A, const __bf16* __restrict__ BT,
    const float* __restrict__ bias, int K, int NBn, int N,
    float* __restrict__ out32)
{
  extern __shared__ __align__(16) char lds[];
  const int tid = threadIdx.x, lane = tid & 63, wid = tid >> 6;
  const int wm = wid >> 2, wn = wid & 3;
  const int lr = lane & 15, lg = lane >> 4;

  const int cpx = gridDim.x >> 3;
  const int id = (blockIdx.x & 7) * cpx + (blockIdx.x >> 3);
  const int m0 = (id / NBn) * 128, n0 = (id % NBn) * 256;

  const int r8  = wid * 8 + (lane >> 3);
  const int csw = ((lane & 7) ^ (lane >> 3)) * 8;

  auto stageA = [&](const __bf16* g, char* dst) {
    #pragma unroll
    for (int i = 0; i < 2; ++i)
      gload16(g + (size_t)(i * 64 + r8) * K + csw, dst + i * 8192 + wid * 1024);
  };
  auto stageB = [&](const __bf16* g, char* dst) {
    #pragma unroll
    for (int i = 0; i < 4; ++i)
      gload16(g + (size_t)(i * 64 + r8) * K + csw, dst + i * 8192 + wid * 1024);
  };

  auto rdA = [&](bf16x8* d, const char* Ab) {
    #pragma unroll
    for (int mf = 0; mf < 4; ++mf) {
      const char* rp = Ab + (wm * 64 + mf * 16 + lr) * 128;
      #pragma unroll
      for (int ks = 0; ks < 2; ++ks)
        d[mf * 2 + ks] = *(const bf16x8*)(rp + (((ks << 2) + lg) ^ (lr & 7)) * 16);
    }
  };
  auto rdB = [&](bf16x8* d, const char* Bb, int nh) {
    #pragma unroll
    for (int nfl = 0; nfl < 2; ++nfl) {
      const char* rp = Bb + (wn * 64 + (nh * 2 + nfl) * 16 + lr) * 128;
      #pragma unroll
      for (int ks = 0; ks < 2; ++ks)
        d[nfl * 2 + ks] = *(const bf16x8*)(rp + (((ks << 2) + lg) ^ (lr & 7)) * 16);
    }
  };

  f32x4 acc[4][4] = {};

  auto mm = [&](const bf16x8* av, const bf16x8* bv, int nh) {
    __builtin_amdgcn_s_setprio(1);
    #pragma unroll
    for (int mf = 0; mf < 4; ++mf)
      #pragma unroll
      for (int nfl = 0; nfl < 2; ++nfl)
        #pragma unroll
        for (int ks = 0; ks < 2; ++ks)
          acc[mf][nh * 2 + nfl] = __builtin_amdgcn_mfma_f32_16x16x32_bf16(
              av[mf * 2 + ks], bv[nfl * 2 + ks], acc[mf][nh * 2 + nfl], 0, 0, 0);
    __builtin_amdgcn_s_setprio(0);
  };

  const int nt = K >> 6;
  const __bf16* gA = A  + (size_t)m0 * K;
  const __bf16* gB = BT + (size_t)n0 * K;
  char* const Ab0 = lds;
  char* const Bb0 = lds + 32768;

  stageB(gB, Bb0);
  stageA(gA, Ab0);
  stageB(gB + 64, Bb0 + 32768);
  stageA(gA + 64, Ab0 + 16384);

  bf16x8 a[8], b0[4], b1[4];

  for (int t = 0; t < nt; ++t) {
    char* Ab = Ab0 + (t & 1) * 16384;
    char* Bb = Bb0 + (t % 3) * 32768;

    if (t + 1 < nt) { asm volatile("s_waitcnt vmcnt(6)\ns_barrier" ::: "memory"); }
    else            { asm volatile("s_waitcnt vmcnt(0)\ns_barrier" ::: "memory"); }
    rdA(a, Ab);
    rdB(b0, Bb, 0);
    if (t + 2 < nt) stageB(gB + (size_t)(t + 2) * 64, Bb0 + ((t + 2) % 3) * 32768);
    mm(a, b0, 0);
    asm volatile("s_barrier" ::: "memory");

    rdB(b1, Bb, 1);
    if (t + 2 < nt) stageA(gA + (size_t)(t + 2) * 64, Ab);
    mm(a, b1, 1);
    asm volatile("s_barrier" ::: "memory");
  }

  #pragma unroll
  for (int nf = 0; nf < 4; ++nf) {
    int n = n0 + wn * 64 + nf * 16 + lr;
    float bv = bias[n];
    #pragma unroll
    for (int mf = 0; mf < 4; ++mf)
      #pragma unroll
      for (int j = 0; j < 4; ++j) {
        int m = m0 + wm * 64 + mf * 16 + lg * 4 + j;
        out32[(size_t)m * N + n] = acc[mf][nf][j] + bv;
      }
  }
}

// ---------------------------------------------------------------------------
// Persistent per-head flash attention (causal). Grid 256 = B*H, 512 threads.
// K/V of the head are read from HBM EXACTLY ONCE: chunk c outer, q-tile
// inner (online softmax still sees chunks in increasing order per row).
// Wave w (p=w>>2, sub=w&3) owns 4 row-groups: (qt = p+2*gi, rows sub*16..)
// with persistent state {qf, acc, m, l} per group. One __syncthreads per
// chunk (double-buffered K/V). V pre-transposed (vt[bh][d][t]).
// ---------------------------------------------------------------------------
__global__ __launch_bounds__(512, 2) void attn_kernel(
    const __bf16* __restrict__ qb, const __bf16* __restrict__ kb,
    const __bf16* __restrict__ vtb, __bf16* __restrict__ y)
{
  __shared__ __attribute__((aligned(16))) __bf16 Ks[2][64][72];
  __shared__ __attribute__((aligned(16))) __bf16 Vt[2][64][72];
  __shared__ __attribute__((aligned(16))) __bf16 Ps[8][16][72];

  const int tid = threadIdx.x, lane = tid & 63, w = tid >> 6;   // 8 waves
  const int lr = lane & 15, lg = lane >> 4;
  const int p = w >> 2, sub = w & 3;
  const int bh = blockIdx.x;
  const size_t base = (size_t)bh * T_ * HD_;
  const int b = bh >> 4, h = bh & 15;
  const float SCALE = 0.03125f;                   // 1/sqrt(1024)
  const float L2E = 1.44269504088896f;

  const int r_  = tid >> 3;                       // 0..63
  const int c8_ = (tid & 7) * 8;

  // persistent per-group state: qt(gi) = p + 2*gi
  bf16x8 qf[4][2];
  #pragma unroll
  for (int gi = 0; gi < 4; ++gi) {
    int q0 = (p + 2 * gi) * 64 + sub * 16;
    #pragma unroll
    for (int s = 0; s < 2; ++s)
      qf[gi][s] = *(const bf16x8*)&qb[base + (size_t)(q0 + lr) * HD_ + s * 32 + lg * 8];
  }
  f32x4 acc[4][4] = {};
  float mrun[4][4], lrun[4][4];
  #pragma unroll
  for (int gi = 0; gi < 4; ++gi)
    #pragma unroll
    for (int j = 0; j < 4; ++j) { mrun[gi][j] = -__builtin_inff(); lrun[gi][j] = 0.f; }

  // chunk 0 into regs (512 threads x 16B = one 64x64 chunk)
  bf16x8 kk, vv, kk2, vv2;
  kk = *(const bf16x8*)&kb[base + (size_t)r_ * HD_ + c8_];
  vv = *(const bf16x8*)&vtb[base + (size_t)r_ * T_ + c8_];

  for (int c = 0; c < 8; ++c) {
    const int cb = c & 1;
    *(bf16x8*)&Ks[cb][r_][c8_] = kk;
    *(bf16x8*)&Vt[cb][r_][c8_] = vv;
    __syncthreads();

    if (c < 7) {                                   // prefetch next chunk
      kk2 = *(const bf16x8*)&kb[base + (size_t)(c + 1) * 64 * HD_ + (size_t)r_ * HD_ + c8_];
      vv2 = *(const bf16x8*)&vtb[base + (size_t)r_ * T_ + (c + 1) * 64 + c8_];
    }

    #pragma unroll
    for (int gi = 0; gi < 4; ++gi) {
      const int qt = p + 2 * gi;
      if (qt < c) continue;                        // wave-uniform
      const int q0 = qt * 64 + sub * 16;

      // ---- S = Q K^T (16 q x 64 kv) ----
      f32x4 sc[4] = {};
      #pragma unroll
      for (int s = 0; s < 2; ++s) {
        #pragma unroll
        for (int cc = 0; cc < 4; ++cc) {
          bf16x8 kf = *(const bf16x8*)&Ks[cb][cc * 16 + lr][s * 32 + lg * 8];
          sc[cc] = __builtin_amdgcn_mfma_f32_16x16x32_bf16(qf[gi][s], kf, sc[cc], 0, 0, 0);
        }
      }

      // ---- scale + causal mask (diagonal chunk only) ----
      #pragma unroll
      for (int cc = 0; cc < 4; ++cc)
        #pragma unroll
        for (int j = 0; j < 4; ++j) {
          float v = sc[cc][j] * SCALE;
          if (qt == c) {
            int kv = c * 64 + cc * 16 + lr;
            int qr = q0 + lg * 4 + j;
            if (kv > qr) v = -__builtin_inff();
          }
          sc[cc][j] = v;
        }

      // ---- online softmax ----
      float mx[4];
      #pragma unroll
      for (int j = 0; j < 4; ++j)
        mx[j] = fmaxf(fmaxf(sc[0][j], sc[1][j]), fmaxf(sc[2][j], sc[3][j]));
      #pragma unroll
      for (int msk = 1; msk <= 8; msk <<= 1)
        #pragma unroll
        for (int j = 0; j < 4; ++j)
          mx[j] = fmaxf(mx[j], __shfl_xor(mx[j], msk, 64));
      float corr[4];
      #pragma unroll
      for (int j = 0; j < 4; ++j) {
        float nm = fmaxf(mrun[gi][j], mx[j]);
        corr[j] = exp2f((mrun[gi][j] - nm) * L2E);
        mrun[gi][j] = nm;
      }
      #pragma unroll
      for (int cc = 0; cc < 4; ++cc)
        #pragma unroll
        for (int j = 0; j < 4; ++j)
          sc[cc][j] = exp2f((sc[cc][j] - mrun[gi][j]) * L2E);
      float rs[4];
      #pragma unroll
      for (int j = 0; j < 4; ++j)
        rs[j] = sc[0][j] + sc[1][j] + sc[2][j] + sc[3][j];
      #pragma unroll
      for (int msk = 1; msk <= 8; msk <<= 1)
        #pragma unroll
        for (int j = 0; j < 4; ++j)
          rs[j] += __shfl_xor(rs[j], msk, 64);
      #pragma unroll
      for (int j = 0; j < 4; ++j)
        lrun[gi][j] = lrun[gi][j] * corr[j] + rs[j];
      #pragma unroll
      for (int dd = 0; dd < 4; ++dd)
        #pragma unroll
        for (int j = 0; j < 4; ++j)
          acc[gi][dd][j] *= corr[j];

      // ---- P: C-layout -> A-layout via per-wave LDS ----
      #pragma unroll
      for (int cc = 0; cc < 4; ++cc)
        #pragma unroll
        for (int j = 0; j < 4; ++j)
          Ps[w][lg * 4 + j][cc * 16 + lr] = (__bf16)sc[cc][j];

      // ---- O += P V ----
      #pragma unroll
      for (int s = 0; s < 2; ++s) {
        bf16x8 pa = *(const bf16x8*)&Ps[w][lr][s * 32 + lg * 8];
        #pragma unroll
        for (int dd = 0; dd < 4; ++dd) {
          bf16x8 vf = *(const bf16x8*)&Vt[cb][dd * 16 + lr][s * 32 + lg * 8];
          acc[gi][dd] = __builtin_amdgcn_mfma_f32_16x16x32_bf16(pa, vf, acc[gi][dd], 0, 0, 0);
        }
      }
    }

    if (c < 7) { kk = kk2; vv = vv2; }
  }

  // ---- normalize + write y[B,T,C] for all 4 groups ----
  #pragma unroll
  for (int gi = 0; gi < 4; ++gi) {
    int q0 = (p + 2 * gi) * 64 + sub * 16;
    #pragma unroll
    for (int dd = 0; dd < 4; ++dd)
      #pragma unroll
      for (int j = 0; j < 4; ++j) {
        int t = q0 + lg * 4 + j;
        int d = dd * 16 + lr;
        y[((size_t)(b * T_ + t)) * C_ + h * HD_ + d] =
            (__bf16)(acc[gi][dd][j] / lrun[gi][j]);
      }
  }
}

// ---------------------------------------------------------------------------
extern "C" void kernel_launch(void* const* d_in, const int* in_sizes, int n_in,
                              void* d_out, int out_size, void* d_ws, size_t ws_size,
                              hipStream_t stream) {
  const float* x    = (const float*)d_in[0];
  const float* wqkv = (const float*)d_in[1];
  const float* bqkv = (const float*)d_in[2];
  const float* wo   = (const float*)d_in[3];
  const float* bo   = (const float*)d_in[4];
  float* out = (float*)d_out;

  char* ws = (char*)d_ws;
  const size_t MB = 1u << 20;
  __bf16* xb    = (__bf16*)(ws);              // 16 MB  x bf16 [8192][1024]
  __bf16* wqt   = (__bf16*)(ws + 16 * MB);    //  6 MB  w_qkv^T bf16 [3072][1024]
  __bf16* wot   = (__bf16*)(ws + 22 * MB);    //  2 MB  w_o^T bf16 [1024][1024]
  __bf16* qbuf  = (__bf16*)(ws + 24 * MB);    // 16 MB  Q [B,H,T,HD]
  __bf16* kbuf  = (__bf16*)(ws + 40 * MB);    // 16 MB  K [B,H,T,HD]
  __bf16* vbuf  = (__bf16*)(ws + 56 * MB);    // 16 MB  V [B,H,T,HD]
  __bf16* ybuf  = (__bf16*)(ws + 56 * MB);    // aliases vbuf (dead after vtr)
  __bf16* vtbuf = (__bf16*)(ws + 72 * MB);    // 16 MB  V^T [B,H,HD,T]

  (void)hipFuncSetAttribute(reinterpret_cast<const void*>(&gemm128_kernel),
                            hipFuncAttributeMaxDynamicSharedMemorySize, 131072);

  const int NX = B_ * T_ * C_;               // 8388608
  cvt_kernel<<<NX / (256 * 8), 256, 0, stream>>>(x, xb, NX);
  tconv_kernel<<<dim3(3 * C_ / 32, C_ / 32), dim3(32, 8), 0, stream>>>(wqkv, wqt, C_, 3 * C_);
  tconv_kernel<<<dim3(C_ / 32, C_ / 32), dim3(32, 8), 0, stream>>>(wo, wot, C_, C_);

  // QKV: 8192/128=64 x 3072/128=24 -> 1536 blocks (~3 blocks/CU resident)
  gemmsq_kernel<<<1536, 256, 0, stream>>>(
      xb, wqt, bqkv, C_, 24, qbuf, kbuf, vbuf);

  vtr_kernel<<<dim3(B_ * H_, T_ / 64), 256, 0, stream>>>(vbuf, vtbuf);

  // persistent per-head attention: 256 blocks (1/CU), K/V read once
  attn_kernel<<<256, 512, 0, stream>>>(qbuf, kbuf, vtbuf, ybuf);

  // out-proj: 64 x 4 -> 256 blocks (1.0 round)
  gemm128_kernel<<<256, 512, 131072, stream>>>(
      ybuf, wot, bo, C_, 4, C_, out);
}

// Round 8
// 139.751 us; speedup vs baseline: 1.1200x; 1.1137x over previous
//
#include <hip/hip_runtime.h>
#include <cstddef>

// ---------------------------------------------------------------------------
// MHA block: y = attn(x@Wqkv+b) @ Wo + bo   (B=16,T=512,C=1024,H=16,hd=64)
// R8: QKV gemmsq (m97 128x128, 3 blk/CU) with V written directly transposed;
//     out-proj moved to the same structure; attn reverted to R5 per-qt-block.
// ---------------------------------------------------------------------------

#define B_  16
#define T_  512
#define C_  1024
#define H_  16
#define HD_ 64

typedef __bf16 bf16x8 __attribute__((ext_vector_type(8)));
typedef float  f32x4  __attribute__((ext_vector_type(4)));

__device__ __forceinline__ void gload16(const void* g, void* lds_dst) {
  __builtin_amdgcn_global_load_lds(
      (const __attribute__((address_space(1))) unsigned int*)g,
      (__attribute__((address_space(3))) unsigned int*)lds_dst, 16, 0, 0);
}

// ------------------------- convert x: fp32 -> bf16 --------------------------
__global__ void cvt_kernel(const float* __restrict__ in, __bf16* __restrict__ out, int n) {
  int i = (blockIdx.x * 256 + threadIdx.x) * 8;
  if (i >= n) return;
  float4 f0 = *(const float4*)&in[i];
  float4 f1 = *(const float4*)&in[i + 4];
  bf16x8 o;
  o[0] = (__bf16)f0.x; o[1] = (__bf16)f0.y; o[2] = (__bf16)f0.z; o[3] = (__bf16)f0.w;
  o[4] = (__bf16)f1.x; o[5] = (__bf16)f1.y; o[6] = (__bf16)f1.z; o[7] = (__bf16)f1.w;
  *(bf16x8*)&out[i] = o;
}

// -------------- transpose+convert: w[K][N] fp32 -> wt[N][K] bf16 ------------
__global__ void tconv_kernel(const float* __restrict__ w, __bf16* __restrict__ wt,
                             int K, int N) {
  __shared__ float tile[32][33];
  int tx = threadIdx.x, ty = threadIdx.y;          // block (32,8)
  int n0 = blockIdx.x * 32, k0 = blockIdx.y * 32;
  #pragma unroll
  for (int i = 0; i < 4; ++i) {
    int r = ty + i * 8;
    tile[r][tx] = w[(size_t)(k0 + r) * N + n0 + tx];
  }
  __syncthreads();
  #pragma unroll
  for (int i = 0; i < 4; ++i) {
    int r = ty + i * 8;
    wt[(size_t)(n0 + r) * K + k0 + tx] = (__bf16)tile[tx][r];
  }
}

// ---------------------------------------------------------------------------
// QKV GEMM, m97-structure: tile 128x128, BK=64, 256 threads (4 waves 2x2),
// wave 64x64 (4x4 16x16 frags), 32KB single-buffered static LDS ->
// ~3 blocks/CU; cross-block overlap hides the per-tile drain.
// Per K-tile: {rd a+b (16 b128); lgkm0+bar; stage(t+1) into SAME bufs;
// 32 MFMA; vmcnt0+bar}. XOR swizzle on frag reads; pre-swizzled global src.
// Epilogue: q,k -> [B,H,T,HD] bf16; V -> [B,H,HD,T] bf16 DIRECTLY
// (ushort4 over j = 4 consecutive t). Fused bias.
// ---------------------------------------------------------------------------
__global__ __launch_bounds__(256) void gemmsq_kernel(
    const __bf16* __restrict__ A, const __bf16* __restrict__ BT,
    const float* __restrict__ bias, int K, int NBn,
    __bf16* __restrict__ oq, __bf16* __restrict__ okk, __bf16* __restrict__ ovt)
{
  __shared__ __attribute__((aligned(16))) char lds[32768];   // A 16KB | B 16KB
  const int tid = threadIdx.x, lane = tid & 63, wid = tid >> 6;  // 4 waves
  const int wm = wid >> 1, wn = wid & 1;          // 2M x 2N
  const int lr = lane & 15, lg = lane >> 4;

  const int cpx = gridDim.x >> 3;                 // bijective XCD swizzle
  const int id = (blockIdx.x & 7) * cpx + (blockIdx.x >> 3);
  const int m0 = (id / NBn) * 128, n0 = (id % NBn) * 128;

  // staging: one issue = 256 lanes x 16B = 4KB = 32 rows of 128B
  const int r8  = wid * 8 + (lane >> 3);          // 0..31
  const int csw = ((lane & 7) ^ (lane >> 3)) * 8; // pre-swizzled col (elems)

  auto stage = [&](const __bf16* g, char* dst) {  // 128x64 tile, 4 issues
    #pragma unroll
    for (int i = 0; i < 4; ++i)
      gload16(g + (size_t)(i * 32 + r8) * K + csw, dst + i * 4096 + wid * 1024);
  };
  auto rd = [&](bf16x8* d, const char* buf, int woff) {   // 8 x ds_read_b128
    #pragma unroll
    for (int f = 0; f < 4; ++f) {
      const char* rp = buf + (woff + f * 16 + lr) * 128;
      #pragma unroll
      for (int ks = 0; ks < 2; ++ks)
        d[f * 2 + ks] = *(const bf16x8*)(rp + (((ks << 2) + lg) ^ (lr & 7)) * 16);
    }
  };

  f32x4 acc[4][4] = {};
  const int nt = K >> 6;                          // 16
  const __bf16* gA = A  + (size_t)m0 * K;
  const __bf16* gB = BT + (size_t)n0 * K;
  char* const Ab = lds;
  char* const Bb = lds + 16384;

  stage(gA, Ab);
  stage(gB, Bb);
  asm volatile("s_waitcnt vmcnt(0)\ns_barrier" ::: "memory");

  bf16x8 a[8], b[8];
  for (int t = 0; t < nt; ++t) {
    rd(a, Ab, wm * 64);
    rd(b, Bb, wn * 64);
    asm volatile("s_waitcnt lgkmcnt(0)\ns_barrier" ::: "memory");  // reads in regs
    if (t + 1 < nt) {                                // overwrite now safe
      stage(gA + (size_t)(t + 1) * 64, Ab);
      stage(gB + (size_t)(t + 1) * 64, Bb);
    }
    __builtin_amdgcn_s_setprio(1);
    #pragma unroll
    for (int mf = 0; mf < 4; ++mf)
      #pragma unroll
      for (int nf = 0; nf < 4; ++nf)
        #pragma unroll
        for (int ks = 0; ks < 2; ++ks)
          acc[mf][nf] = __builtin_amdgcn_mfma_f32_16x16x32_bf16(
              a[mf * 2 + ks], b[nf * 2 + ks], acc[mf][nf], 0, 0, 0);
    __builtin_amdgcn_s_setprio(0);
    asm volatile("s_waitcnt vmcnt(0)\ns_barrier" ::: "memory");    // t+1 landed
  }

  // ---- epilogue: D row = lg*4+j, col = lr per 16x16 frag ----
  #pragma unroll
  for (int nf = 0; nf < 4; ++nf) {
    int n = n0 + wn * 64 + nf * 16 + lr;
    float bv = bias[n];
    int which = n >> 10;
    int h = (n >> 6) & 15, d = n & 63;
    if (which == 2) {
      // V -> vt[b][h][d][t], pack 4 consecutive t (j) into one 8B store
      #pragma unroll
      for (int mf = 0; mf < 4; ++mf) {
        int m = m0 + wm * 64 + mf * 16 + lg * 4;      // j=0 row
        int bb = m >> 9, t0 = m & 511;
        ushort4 pk;
        __bf16 e0 = (__bf16)(acc[mf][nf][0] + bv);
        __bf16 e1 = (__bf16)(acc[mf][nf][1] + bv);
        __bf16 e2 = (__bf16)(acc[mf][nf][2] + bv);
        __bf16 e3 = (__bf16)(acc[mf][nf][3] + bv);
        pk.x = *(unsigned short*)&e0; pk.y = *(unsigned short*)&e1;
        pk.z = *(unsigned short*)&e2; pk.w = *(unsigned short*)&e3;
        *(ushort4*)&ovt[(size_t)((bb * H_ + h) * HD_ + d) * T_ + t0] = pk;
      }
    } else {
      __bf16* dst = (which == 0) ? oq : okk;
      #pragma unroll
      for (int mf = 0; mf < 4; ++mf)
        #pragma unroll
        for (int j = 0; j < 4; ++j) {
          int m = m0 + wm * 64 + mf * 16 + lg * 4 + j;
          int bb = m >> 9, tt = m & 511;
          dst[(size_t)((bb * H_ + h) * T_ + tt) * HD_ + d] =
              (__bf16)(acc[mf][nf][j] + bv);
        }
    }
  }
}

// ---------------------------------------------------------------------------
// Out-proj GEMM, same m97 structure: tile 128x128, 256 thr, 32KB LDS,
// fp32 output with fused bias. Grid 64x8 = 512 blocks (~2 blocks/CU).
// ---------------------------------------------------------------------------
__global__ __launch_bounds__(256) void gemmsq_o_kernel(
    const __bf16* __restrict__ A, const __bf16* __restrict__ BT,
    const float* __restrict__ bias, int K, int NBn, int N,
    float* __restrict__ out32)
{
  __shared__ __attribute__((aligned(16))) char lds[32768];
  const int tid = threadIdx.x, lane = tid & 63, wid = tid >> 6;
  const int wm = wid >> 1, wn = wid & 1;
  const int lr = lane & 15, lg = lane >> 4;

  const int cpx = gridDim.x >> 3;
  const int id = (blockIdx.x & 7) * cpx + (blockIdx.x >> 3);
  const int m0 = (id / NBn) * 128, n0 = (id % NBn) * 128;

  const int r8  = wid * 8 + (lane >> 3);
  const int csw = ((lane & 7) ^ (lane >> 3)) * 8;

  auto stage = [&](const __bf16* g, char* dst) {
    #pragma unroll
    for (int i = 0; i < 4; ++i)
      gload16(g + (size_t)(i * 32 + r8) * K + csw, dst + i * 4096 + wid * 1024);
  };
  auto rd = [&](bf16x8* d, const char* buf, int woff) {
    #pragma unroll
    for (int f = 0; f < 4; ++f) {
      const char* rp = buf + (woff + f * 16 + lr) * 128;
      #pragma unroll
      for (int ks = 0; ks < 2; ++ks)
        d[f * 2 + ks] = *(const bf16x8*)(rp + (((ks << 2) + lg) ^ (lr & 7)) * 16);
    }
  };

  f32x4 acc[4][4] = {};
  const int nt = K >> 6;
  const __bf16* gA = A  + (size_t)m0 * K;
  const __bf16* gB = BT + (size_t)n0 * K;
  char* const Ab = lds;
  char* const Bb = lds + 16384;

  stage(gA, Ab);
  stage(gB, Bb);
  asm volatile("s_waitcnt vmcnt(0)\ns_barrier" ::: "memory");

  bf16x8 a[8], b[8];
  for (int t = 0; t < nt; ++t) {
    rd(a, Ab, wm * 64);
    rd(b, Bb, wn * 64);
    asm volatile("s_waitcnt lgkmcnt(0)\ns_barrier" ::: "memory");
    if (t + 1 < nt) {
      stage(gA + (size_t)(t + 1) * 64, Ab);
      stage(gB + (size_t)(t + 1) * 64, Bb);
    }
    __builtin_amdgcn_s_setprio(1);
    #pragma unroll
    for (int mf = 0; mf < 4; ++mf)
      #pragma unroll
      for (int nf = 0; nf < 4; ++nf)
        #pragma unroll
        for (int ks = 0; ks < 2; ++ks)
          acc[mf][nf] = __builtin_amdgcn_mfma_f32_16x16x32_bf16(
              a[mf * 2 + ks], b[nf * 2 + ks], acc[mf][nf], 0, 0, 0);
    __builtin_amdgcn_s_setprio(0);
    asm volatile("s_waitcnt vmcnt(0)\ns_barrier" ::: "memory");
  }

  #pragma unroll
  for (int nf = 0; nf < 4; ++nf) {
    int n = n0 + wn * 64 + nf * 16 + lr;
    float bv = bias[n];
    #pragma unroll
    for (int mf = 0; mf < 4; ++mf)
      #pragma unroll
      for (int j = 0; j < 4; ++j) {
        int m = m0 + wm * 64 + mf * 16 + lg * 4 + j;
        out32[(size_t)m * N + n] = acc[mf][nf][j] + bv;
      }
  }
}

// ---------------------------------------------------------------------------
// Flash attention (causal), R5-proven. Grid (B*H, T/64). 4 waves, 16 q-rows
// each. V pre-transposed (vt[bh][d][t]); K/V staged via register prefetch.
// ---------------------------------------------------------------------------
__global__ __launch_bounds__(256, 2) void attn_kernel(
    const __bf16* __restrict__ qb, const __bf16* __restrict__ kb,
    const __bf16* __restrict__ vtb, __bf16* __restrict__ y)
{
  __shared__ __attribute__((aligned(16))) __bf16 Ks[64][72];
  __shared__ __attribute__((aligned(16))) __bf16 Vt[64][72];
  __shared__ __attribute__((aligned(16))) __bf16 Ps[4][16][72];

  const int tid = threadIdx.x, lane = tid & 63, w = tid >> 6;
  const int lr = lane & 15, lg = lane >> 4;
  const int bh = blockIdx.x, qt = blockIdx.y;
  const size_t base = (size_t)bh * T_ * HD_;
  const int q0 = qt * 64 + w * 16;
  const float SCALE = 0.03125f;                   // 1/sqrt(1024)
  const float L2E = 1.44269504088896f;

  const int r_  = tid >> 3;                       // 0..31 (+32 for p=1)
  const int c8_ = (tid & 7) * 8;

  bf16x8 qf[2];
  #pragma unroll
  for (int s = 0; s < 2; ++s)
    qf[s] = *(const bf16x8*)&qb[base + (size_t)(q0 + lr) * HD_ + s * 32 + lg * 8];

  f32x4 acc[4] = {};
  float mrun[4] = { -__builtin_inff(), -__builtin_inff(),
                    -__builtin_inff(), -__builtin_inff() };
  float lrun[4] = { 0.f, 0.f, 0.f, 0.f };

  bf16x8 kk[2], vv[2], kk2[2], vv2[2];
  #pragma unroll
  for (int p = 0; p < 2; ++p) {
    int rr = p * 32 + r_;
    kk[p] = *(const bf16x8*)&kb[base + (size_t)rr * HD_ + c8_];
    vv[p] = *(const bf16x8*)&vtb[base + (size_t)rr * T_ + c8_];
  }

  for (int c = 0; c <= qt; ++c) {
    #pragma unroll
    for (int p = 0; p < 2; ++p) {
      int rr = p * 32 + r_;
      *(bf16x8*)&Ks[rr][c8_] = kk[p];
      *(bf16x8*)&Vt[rr][c8_] = vv[p];
    }
    __syncthreads();

    if (c < qt) {
      #pragma unroll
      for (int p = 0; p < 2; ++p) {
        int rr = p * 32 + r_;
        kk2[p] = *(const bf16x8*)&kb[base + (size_t)(c + 1) * 64 * HD_ + (size_t)rr * HD_ + c8_];
        vv2[p] = *(const bf16x8*)&vtb[base + (size_t)rr * T_ + (c + 1) * 64 + c8_];
      }
    }

    f32x4 sc[4] = {};
    #pragma unroll
    for (int s = 0; s < 2; ++s) {
      #pragma unroll
      for (int cc = 0; cc < 4; ++cc) {
        bf16x8 kf = *(const bf16x8*)&Ks[cc * 16 + lr][s * 32 + lg * 8];
        sc[cc] = __builtin_amdgcn_mfma_f32_16x16x32_bf16(qf[s], kf, sc[cc], 0, 0, 0);
      }
    }

    #pragma unroll
    for (int cc = 0; cc < 4; ++cc)
      #pragma unroll
      for (int j = 0; j < 4; ++j) {
        float v = sc[cc][j] * SCALE;
        if (c == qt) {
          int kv = c * 64 + cc * 16 + lr;
          int qr = q0 + lg * 4 + j;
          if (kv > qr) v = -__builtin_inff();
        }
        sc[cc][j] = v;
      }

    float mx[4];
    #pragma unroll
    for (int j = 0; j < 4; ++j)
      mx[j] = fmaxf(fmaxf(sc[0][j], sc[1][j]), fmaxf(sc[2][j], sc[3][j]));
    #pragma unroll
    for (int msk = 1; msk <= 8; msk <<= 1)
      #pragma unroll
      for (int j = 0; j < 4; ++j)
        mx[j] = fmaxf(mx[j], __shfl_xor(mx[j], msk, 64));
    float corr[4];
    #pragma unroll
    for (int j = 0; j < 4; ++j) {
      float nm = fmaxf(mrun[j], mx[j]);
      corr[j] = exp2f((mrun[j] - nm) * L2E);
      mrun[j] = nm;
    }
    #pragma unroll
    for (int cc = 0; cc < 4; ++cc)
      #pragma unroll
      for (int j = 0; j < 4; ++j)
        sc[cc][j] = exp2f((sc[cc][j] - mrun[j]) * L2E);
    float rs[4];
    #pragma unroll
    for (int j = 0; j < 4; ++j)
      rs[j] = sc[0][j] + sc[1][j] + sc[2][j] + sc[3][j];
    #pragma unroll
    for (int msk = 1; msk <= 8; msk <<= 1)
      #pragma unroll
      for (int j = 0; j < 4; ++j)
        rs[j] += __shfl_xor(rs[j], msk, 64);
    #pragma unroll
    for (int j = 0; j < 4; ++j)
      lrun[j] = lrun[j] * corr[j] + rs[j];
    #pragma unroll
    for (int dd = 0; dd < 4; ++dd)
      #pragma unroll
      for (int j = 0; j < 4; ++j)
        acc[dd][j] *= corr[j];

    #pragma unroll
    for (int cc = 0; cc < 4; ++cc)
      #pragma unroll
      for (int j = 0; j < 4; ++j)
        Ps[w][lg * 4 + j][cc * 16 + lr] = (__bf16)sc[cc][j];

    #pragma unroll
    for (int s = 0; s < 2; ++s) {
      bf16x8 pa = *(const bf16x8*)&Ps[w][lr][s * 32 + lg * 8];
      #pragma unroll
      for (int dd = 0; dd < 4; ++dd) {
        bf16x8 vf = *(const bf16x8*)&Vt[dd * 16 + lr][s * 32 + lg * 8];
        acc[dd] = __builtin_amdgcn_mfma_f32_16x16x32_bf16(pa, vf, acc[dd], 0, 0, 0);
      }
    }
    __syncthreads();
    #pragma unroll
    for (int p = 0; p < 2; ++p) { kk[p] = kk2[p]; vv[p] = vv2[p]; }
  }

  const int b = bh >> 4, h = bh & 15;
  #pragma unroll
  for (int dd = 0; dd < 4; ++dd)
    #pragma unroll
    for (int j = 0; j < 4; ++j) {
      int t = q0 + lg * 4 + j;
      int d = dd * 16 + lr;
      y[((size_t)(b * T_ + t)) * C_ + h * HD_ + d] = (__bf16)(acc[dd][j] / lrun[j]);
    }
}

// ---------------------------------------------------------------------------
extern "C" void kernel_launch(void* const* d_in, const int* in_sizes, int n_in,
                              void* d_out, int out_size, void* d_ws, size_t ws_size,
                              hipStream_t stream) {
  const float* x    = (const float*)d_in[0];
  const float* wqkv = (const float*)d_in[1];
  const float* bqkv = (const float*)d_in[2];
  const float* wo   = (const float*)d_in[3];
  const float* bo   = (const float*)d_in[4];
  float* out = (float*)d_out;

  char* ws = (char*)d_ws;
  const size_t MB = 1u << 20;
  __bf16* xb    = (__bf16*)(ws);              // 16 MB  x bf16 [8192][1024]
  __bf16* wqt   = (__bf16*)(ws + 16 * MB);    //  6 MB  w_qkv^T bf16 [3072][1024]
  __bf16* wot   = (__bf16*)(ws + 22 * MB);    //  2 MB  w_o^T bf16 [1024][1024]
  __bf16* qbuf  = (__bf16*)(ws + 24 * MB);    // 16 MB  Q [B,H,T,HD]
  __bf16* kbuf  = (__bf16*)(ws + 40 * MB);    // 16 MB  K [B,H,T,HD]
  __bf16* vtbuf = (__bf16*)(ws + 56 * MB);    // 16 MB  V^T [B,H,HD,T] (direct)
  __bf16* ybuf  = (__bf16*)(ws + 72 * MB);    // 16 MB  attn out [B,T,C]

  const int NX = B_ * T_ * C_;               // 8388608
  cvt_kernel<<<NX / (256 * 8), 256, 0, stream>>>(x, xb, NX);
  tconv_kernel<<<dim3(3 * C_ / 32, C_ / 32), dim3(32, 8), 0, stream>>>(wqkv, wqt, C_, 3 * C_);
  tconv_kernel<<<dim3(C_ / 32, C_ / 32), dim3(32, 8), 0, stream>>>(wo, wot, C_, C_);

  // QKV: 64 x 24 -> 1536 blocks (~3 blocks/CU resident); V written transposed
  gemmsq_kernel<<<1536, 256, 0, stream>>>(
      xb, wqt, bqkv, C_, 24, qbuf, kbuf, vtbuf);

  attn_kernel<<<dim3(B_ * H_, T_ / 64), 256, 0, stream>>>(qbuf, kbuf, vtbuf, ybuf);

  // out-proj: 64 x 8 -> 512 blocks (~2 blocks/CU)
  gemmsq_o_kernel<<<512, 256, 0, stream>>>(
      ybuf, wot, bo, C_, 8, C_, out);
}